// Round 10
// baseline (567.763 us; speedup 1.0000x reference)
//
#include <hip/hip_runtime.h>
#include <hip/hip_bf16.h>

typedef __hip_bfloat16 bf16;
typedef __attribute__((ext_vector_type(8))) short short8;
typedef __attribute__((ext_vector_type(4))) float f32x4;

#define DD    172      // D
#define EE    172      // E
#define QIN   272      // D+T
#define KK    20
#define HH    2
#define DHH   86
#define N0C   512
#define N1C   10240
#define M1    204800   // N1*K rows
#define M0    10240    // N0*K rows

// GEMM geometry
#define BM   128
#define BN   176
#define BK   64
#define KP   448       // kv_in padded K (444 -> 448)
#define NKV  344       // kv row stride (k|v)
#define NPADR 384      // wkvT rows per layer
#define QS   320       // qin padded K
#define F1S  384       // f1in padded K
#define HS   192       // h padded K

// L3-blocked chunk: 40960 rows = 2048 nodes = 320 m-tiles; A-slice 36.7 MB,
// kv-slice 28 MB -> stage->gemm->attn working set ~65 MB stays in the 256 MB
// Infinity Cache; the A-buffer is REUSED across chunks (write-back absorbed).
#define CHUNK_ROWS 40960

#define GLOAD(src, dst) __builtin_amdgcn_global_load_lds( \
    (const __attribute__((address_space(1))) unsigned int*)(src), \
    (__attribute__((address_space(3))) unsigned int*)(dst), 16, 0, 0)

__device__ __forceinline__ float bfu2f(unsigned short u) {
    return __uint_as_float(((unsigned)u) << 16);
}

// fast cos: x -> revolutions -> v_fract -> v_cos (verified r7/r8: absmax unchanged)
__device__ __forceinline__ float fastcos(float x) {
    float r = x * 0.15915494309189535f;
    r = __builtin_amdgcn_fractf(r);
    return __builtin_amdgcn_cosf(r);
}

__device__ __forceinline__ unsigned pack2bf(float a, float b) {
    union { bf16 h[2]; unsigned u; } p;
    p.h[0] = __float2bfloat16(a);
    p.h[1] = __float2bfloat16(b);
    return p.u;
}

__device__ __forceinline__ bool get_mask(const void* m, int mode, int idx) {
    if (mode == 1) return ((const unsigned char*)m)[idx] != 0;
    if (mode == 2) return ((const float*)m)[idx] != 0.0f;
    return ((const int*)m)[idx] != 0;
}

// ---------------- mega prep: wkvT + 6 wT jobs + mask probe, one launch ---
// block ranges: [0,1344) wkvT | [1344,1824) wq | [1824,2400) f1 | [2400,2688) f2 | 2688 probe
__global__ void prep_mega_kernel(
    const float* __restrict__ wk, const float* __restrict__ wv,
    const float* __restrict__ bk, const float* __restrict__ bv,
    const float* __restrict__ wq, const float* __restrict__ bq,
    const float* __restrict__ f1w, const float* __restrict__ f1b,
    const float* __restrict__ f2w, const float* __restrict__ f2b,
    bf16* __restrict__ wkvT, float* __restrict__ biaskv,
    bf16* __restrict__ wqT, float* __restrict__ biasq,
    bf16* __restrict__ f1T, float* __restrict__ biasf1,
    bf16* __restrict__ f2T, float* __restrict__ biasf2,
    const unsigned* __restrict__ maskw, int n_ints, int* __restrict__ mode_out) {
    int blk = blockIdx.x;
    if (blk < 1344) {
        size_t i = (size_t)blk * 256 + threadIdx.x;
        size_t tot = (size_t)2 * NPADR * KP;
        if (i < tot) {
            int l = (int)(i / ((size_t)NPADR * KP));
            int rem = (int)(i % ((size_t)NPADR * KP));
            int k = rem / NPADR;
            int n = rem % NPADR;
            float v = 0.f;
            if (k < 444) {
                if (n < DD)          v = wk[((size_t)l * 444 + k) * DD + n];
                else if (n < 2 * DD) v = wv[((size_t)l * 444 + k) * DD + (n - DD)];
            }
            wkvT[((size_t)l * NPADR + n) * KP + k] = __float2bfloat16(v);
            if (i < 2 * 352) {
                int nn = (int)(i % 352), ll = (int)(i / 352);
                biaskv[i] = nn < DD ? bk[ll * DD + nn] : (nn < 2 * DD ? bv[ll * DD + nn - DD] : 0.f);
            }
        }
        return;
    }
    if (blk < 2688) {
        int job;
        const float* W; const float* b; bf16* dstT; float* biasdst; int K, KPdst;
        if (blk < 1824)      { job = blk - 1344; }
        else if (blk < 2400) { job = blk - 1824; }
        else                 { job = blk - 2400; }
        int per = (blk < 1824) ? 240 : (blk < 2400) ? 288 : 144;
        int l = job / per;
        int sub = job % per;
        if (blk < 1824)      { W = wq  + (size_t)l * QIN * DD; b = bq  + (size_t)l * DD; dstT = wqT + (size_t)l * 192 * QS;  biasdst = biasq  + l * 176; K = QIN; KPdst = QS;  }
        else if (blk < 2400) { W = f1w + (size_t)l * 344 * DD; b = f1b + (size_t)l * DD; dstT = f1T + (size_t)l * 192 * F1S; biasdst = biasf1 + l * 176; K = 344; KPdst = F1S; }
        else                 { W = f2w + (size_t)l * DD * DD;  b = f2b + (size_t)l * DD; dstT = f2T + (size_t)l * 192 * HS;  biasdst = biasf2 + l * 176; K = DD;  KPdst = HS;  }
        int i = sub * 256 + threadIdx.x;
        int tot = 192 * KPdst;
        if (i < tot) {
            int n = i / KPdst, k = i % KPdst;
            float v = (n < DD && k < K) ? W[(size_t)k * DD + n] : 0.f;
            dstT[(size_t)n * KPdst + k] = __float2bfloat16(v);
        }
        if (i < 176) biasdst[i] = (i < DD) ? b[i] : 0.f;
        return;
    }
    // probe job (1 block)
    __shared__ int c_other, c_float;
    if (threadIdx.x == 0) { c_other = 0; c_float = 0; }
    __syncthreads();
    int lo = 0, lf = 0;
    for (int i = threadIdx.x; i < n_ints; i += blockDim.x) {
        unsigned v = maskw[i];
        if (v == 0x3F800000u) lf++;
        else if (v > 1u) lo++;
    }
    if (lo) atomicAdd(&c_other, lo);
    if (lf) atomicAdd(&c_float, lf);
    __syncthreads();
    if (threadIdx.x == 0) {
        int mode = 0;
        if (c_float > 0) mode = 2;
        else if (c_other > 0) mode = 1;
        *mode_out = mode;
    }
}

// ---------------- kv_in staging: [nbr_feat | edge | cos(dt*w+b) | 0pad] --
// pair-per-lane: cols (2l, 2l+1) — region boundaries (172/344/444) are even,
// so a pair never straddles. float2 loads, 4B packed-bf16 stores, stride-1.
__global__ __launch_bounds__(256) void stage_kvin_kernel(
    const float* __restrict__ sf, const int* __restrict__ nbrs,
    const float* __restrict__ edge, const float* __restrict__ times,
    const float* __restrict__ nbrt,
    const void* __restrict__ mask, const int* __restrict__ mode_p,
    const float* __restrict__ time_w, const float* __restrict__ time_b,
    const float* __restrict__ zbuf, const int* __restrict__ g2l, int use_z,
    int row0, bf16* __restrict__ out) {
    int wave = threadIdx.x >> 6, lane = threadIdx.x & 63;
    int lrow = blockIdx.x * 4 + wave;
    int row = row0 + lrow;
    int mode = *mode_p;
    int g = nbrs[row];
    bool mk = get_mask(mask, mode, row);
    float dt = mk ? (times[row / KK] - nbrt[row]) : 0.f;
    const float* src = (use_z && mk) ? (zbuf + (size_t)g2l[g] * DD)
                                     : (sf + (size_t)g * DD);
    const float* erow = edge + (size_t)row * EE;
    bf16* orow = out + (size_t)lrow * KP;
#pragma unroll
    for (int i2 = 0; i2 < KP; i2 += 128) {
        int col = i2 + 2 * lane;
        if (col >= KP) break;
        float v0, v1;
        if (col < DD) {
            float2 u = *(const float2*)(src + col);
            v0 = u.x; v1 = u.y;
        } else if (col < DD + EE) {
            float2 u = *(const float2*)(erow + (col - DD));
            v0 = u.x; v1 = u.y;
        } else if (col < 444) {
            int t = col - DD - EE;
            v0 = fastcos(dt * time_w[t] + time_b[t]);
            v1 = fastcos(dt * time_w[t + 1] + time_b[t + 1]);
        } else {
            v0 = 0.f; v1 = 0.f;
        }
        *(unsigned*)(orow + col) = pack2bf(v0, v1);
    }
}

// ---------------- q_in staging: [feat | cos(time_b) | 0pad] -------------
__global__ __launch_bounds__(256) void stage_qin_kernel(
    const float* __restrict__ sf, const int* __restrict__ idx,
    const float* __restrict__ time_b, bf16* __restrict__ out) {
    int wave = threadIdx.x >> 6, lane = threadIdx.x & 63;
    int row = blockIdx.x * 4 + wave;
    const float* src = sf + (size_t)idx[row] * DD;
    bf16* orow = out + (size_t)row * QS;
#pragma unroll
    for (int i2 = 0; i2 < QS; i2 += 128) {
        int col = i2 + 2 * lane;
        if (col >= QS) break;
        float v0, v1;
        if (col < DD) {
            float2 u = *(const float2*)(src + col);
            v0 = u.x; v1 = u.y;
        } else if (col < QIN) {
            v0 = fastcos(time_b[col - DD]);
            v1 = fastcos(time_b[col - DD + 1]);
        } else {
            v0 = 0.f; v1 = 0.f;
        }
        *(unsigned*)(orow + col) = pack2bf(v0, v1);
    }
}

// ---------------- MFMA GEMM (kv): kv[m][0:344] = A @ wkvT^T + bias ------
// XCD-paired n-tiles (blocks b, b+8 same XCD -> A tile L2-shared).
__global__ __launch_bounds__(256) void gemm_kv_kernel(
    const bf16* __restrict__ A, const bf16* __restrict__ BT,
    const float* __restrict__ bias, bf16* __restrict__ kvout, int Mtiles) {
    int bid = blockIdx.x;
    int mt, nt;
    if ((Mtiles & 7) == 0) {
        nt = (bid >> 3) & 1;
        mt = (bid & 7) + ((bid >> 4) << 3);
    } else {
        mt = bid % Mtiles;
        nt = bid / Mtiles;
    }
    int m0 = mt * BM;
    int n0 = nt * BN;
    __shared__ bf16 As[BM][BK];
    __shared__ bf16 Bs[192][BK];
    int tid = threadIdx.x;
    int lane = tid & 63;
    int wave = tid >> 6;
    int ml = lane & 15;
    int kg = lane >> 4;

    f32x4 acc[2][11];
#pragma unroll
    for (int mg = 0; mg < 2; ++mg)
#pragma unroll
        for (int fn = 0; fn < 11; ++fn)
            acc[mg][fn] = (f32x4){0.f, 0.f, 0.f, 0.f};

    for (int kk = 0; kk < KP; kk += BK) {
        int c0 = tid;
#pragma unroll
        for (int it = 0; it < 4; ++it) {
            int c = it * 256 + c0;
            int row = c >> 3, slot = c & 7;
            int sslot = slot ^ (row & 7);
            const bf16* src = A + (size_t)(m0 + row) * KP + kk + sslot * 8;
            GLOAD(src, ((char*)As) + (size_t)(it * 256 + wave * 64) * 16);
        }
#pragma unroll
        for (int it = 0; it < 6; ++it) {
            int c = it * 256 + c0;
            int row = c >> 3, slot = c & 7;
            int sslot = slot ^ (row & 7);
            const bf16* src = BT + (size_t)(n0 + row) * KP + kk + sslot * 8;
            GLOAD(src, ((char*)Bs) + (size_t)(it * 256 + wave * 64) * 16);
        }
        __syncthreads();
#pragma unroll
        for (int half = 0; half < 2; ++half) {
            int kc = kg + half * 4;
            short8 a[2], b[11];
#pragma unroll
            for (int mg = 0; mg < 2; ++mg) {
                int r = wave * 32 + mg * 16 + ml;
                a[mg] = *(const short8*)(((const char*)As) + (size_t)r * 128 + ((size_t)(kc ^ (r & 7)) << 4));
            }
#pragma unroll
            for (int fn = 0; fn < 11; ++fn) {
                int r = fn * 16 + ml;
                b[fn] = *(const short8*)(((const char*)Bs) + (size_t)r * 128 + ((size_t)(kc ^ (r & 7)) << 4));
            }
#pragma unroll
            for (int mg = 0; mg < 2; ++mg)
#pragma unroll
                for (int fn = 0; fn < 11; ++fn)
                    acc[mg][fn] = __builtin_amdgcn_mfma_f32_16x16x32_bf16(a[mg], b[fn], acc[mg][fn], 0, 0, 0);
        }
        __syncthreads();
    }
#pragma unroll
    for (int mg = 0; mg < 2; ++mg)
#pragma unroll
        for (int fn = 0; fn < 11; ++fn) {
            int col = n0 + fn * 16 + ml;
            if (col < NKV) {
                float bb = bias[col];
#pragma unroll
                for (int r4 = 0; r4 < 4; ++r4) {
                    int row = m0 + wave * 32 + mg * 16 + kg * 4 + r4;
                    kvout[(size_t)row * NKV + col] = __float2bfloat16(acc[mg][fn][r4] + bb);
                }
            }
        }
}

// ---------------- generic 176-col MFMA GEMM -----------------------------
// OMODE: 0 = bf16 dense (stride ostride, zero pad cols 176..ostride),
//        1 = fp32 dense (cols < 172), 2 = fp32 scatter rows via g2l[idx[row]]
template<int KP_, bool RELU, int OMODE>
__global__ __launch_bounds__(256) void gemm176_kernel(
    const bf16* __restrict__ A, const bf16* __restrict__ BT,
    const float* __restrict__ bias, void* __restrict__ outp, int ostride,
    const int* __restrict__ idx, const int* __restrict__ g2l) {
    int m0 = blockIdx.x * BM;
    __shared__ bf16 As[BM][BK];
    __shared__ bf16 Bs[192][BK];
    int tid = threadIdx.x;
    int lane = tid & 63;
    int wave = tid >> 6;
    int ml = lane & 15;
    int kg = lane >> 4;

    f32x4 acc[2][11];
#pragma unroll
    for (int mg = 0; mg < 2; ++mg)
#pragma unroll
        for (int fn = 0; fn < 11; ++fn)
            acc[mg][fn] = (f32x4){0.f, 0.f, 0.f, 0.f};

    for (int kk = 0; kk < KP_; kk += BK) {
        int c0 = tid;
#pragma unroll
        for (int it = 0; it < 4; ++it) {
            int c = it * 256 + c0;
            int row = c >> 3, slot = c & 7;
            int sslot = slot ^ (row & 7);
            const bf16* src = A + (size_t)(m0 + row) * KP_ + kk + sslot * 8;
            GLOAD(src, ((char*)As) + (size_t)(it * 256 + wave * 64) * 16);
        }
#pragma unroll
        for (int it = 0; it < 6; ++it) {
            int c = it * 256 + c0;
            int row = c >> 3, slot = c & 7;
            int sslot = slot ^ (row & 7);
            const bf16* src = BT + (size_t)row * KP_ + kk + sslot * 8;
            GLOAD(src, ((char*)Bs) + (size_t)(it * 256 + wave * 64) * 16);
        }
        __syncthreads();
#pragma unroll
        for (int half = 0; half < 2; ++half) {
            int kc = kg + half * 4;
            short8 a[2], b[11];
#pragma unroll
            for (int mg = 0; mg < 2; ++mg) {
                int r = wave * 32 + mg * 16 + ml;
                a[mg] = *(const short8*)(((const char*)As) + (size_t)r * 128 + ((size_t)(kc ^ (r & 7)) << 4));
            }
#pragma unroll
            for (int fn = 0; fn < 11; ++fn) {
                int r = fn * 16 + ml;
                b[fn] = *(const short8*)(((const char*)Bs) + (size_t)r * 128 + ((size_t)(kc ^ (r & 7)) << 4));
            }
#pragma unroll
            for (int mg = 0; mg < 2; ++mg)
#pragma unroll
                for (int fn = 0; fn < 11; ++fn)
                    acc[mg][fn] = __builtin_amdgcn_mfma_f32_16x16x32_bf16(a[mg], b[fn], acc[mg][fn], 0, 0, 0);
        }
        __syncthreads();
    }
#pragma unroll
    for (int mg = 0; mg < 2; ++mg)
#pragma unroll
        for (int fn = 0; fn < 11; ++fn) {
            int col = fn * 16 + ml;
            float bb = bias[col];
#pragma unroll
            for (int r4 = 0; r4 < 4; ++r4) {
                int row = m0 + wave * 32 + mg * 16 + kg * 4 + r4;
                float v = acc[mg][fn][r4] + bb;
                if (RELU) v = fmaxf(v, 0.f);
                if (OMODE == 0) {
                    ((bf16*)outp)[(size_t)row * ostride + col] = __float2bfloat16(v);
                } else if (OMODE == 1) {
                    if (col < DD) ((float*)outp)[(size_t)row * ostride + col] = v;
                } else {
                    if (col < DD) {
                        int zr = g2l[idx[row]];
                        ((float*)outp)[(size_t)zr * DD + col] = v;
                    }
                }
            }
        }
    if (OMODE == 0 && ostride > 176) {
        int row = tid >> 1, half = tid & 1;
        short8 zz = (short8){0, 0, 0, 0, 0, 0, 0, 0};
        *(short8*)&((bf16*)outp)[(size_t)(m0 + row) * ostride + 176 + half * 8] = zz;
    }
}

// ---------------- attention over K=20 neighbors (kv packed [row][344]) --
// node0: chunk offset so attn runs per-chunk while kv slice is L3-hot.
#define ASTR 360
__global__ __launch_bounds__(64) void attn_kernel(
    const float* __restrict__ q, const bf16* __restrict__ kv,
    const void* __restrict__ mask, const int* __restrict__ mode_p,
    const float* __restrict__ sf, const int* __restrict__ idx,
    bf16* __restrict__ f1out, int node0) {
    int node = node0 + blockIdx.x;
    int lane = threadIdx.x;
    __shared__ unsigned short kvls[KK][ASTR];
    __shared__ float qs[DD];
    __shared__ float sc[HH][KK];
    __shared__ float aw[HH][KK];
    int mode = *mode_p;
    const unsigned short* kvg = (const unsigned short*)(kv + (size_t)node * KK * NKV);
    for (int c = lane; c < 860; c += 64) {          // 20*344/8 = 860 chunks
        int r = c / 43, cc = c % 43;
        *(short8*)&kvls[r][cc * 8] = *(const short8*)(kvg + (size_t)c * 8);
    }
    for (int i = lane; i < DD; i += 64) qs[i] = q[(size_t)node * DD + i];
    __syncthreads();
    if (lane < HH * KK) {
        int h = lane / KK, kx = lane % KK;
        bool mk = get_mask(mask, mode, node * KK + kx);
        float s = 0.f;
        const unsigned short* kr = &kvls[kx][h * DHH];
        for (int d = 0; d < DHH; d++) s += qs[h * DHH + d] * bfu2f(kr[d]);
        sc[h][kx] = mk ? s * 0.10783277320f : -3.0e38f;
    }
    __syncthreads();
    if (lane < HH) {
        int h = lane;
        float m = -3.0e38f;
        for (int k2 = 0; k2 < KK; k2++) m = fmaxf(m, sc[h][k2]);
        float den = 0.f;
        for (int k2 = 0; k2 < KK; k2++) {
            float e = (sc[h][k2] <= -1e37f) ? 0.f : expf(sc[h][k2] - m);
            sc[h][k2] = e;
            den += e;
        }
        float inv = (den > 0.f) ? 1.f / den : 0.f;
        for (int k2 = 0; k2 < KK; k2++) aw[h][k2] = sc[h][k2] * inv;
    }
    __syncthreads();
    bf16* orow = f1out + (size_t)node * F1S;
    for (int jj = lane; jj < DD; jj += 64) {
        int h = jj / DHH;
        float s = 0.f;
        for (int k2 = 0; k2 < KK; k2++)
            s += aw[h][k2] * bfu2f(kvls[k2][DD + jj]);
        orow[jj] = __float2bfloat16(s);
    }
    const float* src = sf + (size_t)idx[node] * DD;
    for (int c = lane; c < F1S - DD; c += 64) {     // cols 172..383: nf then 0
        float v = (c < DD) ? src[c] : 0.f;
        orow[DD + c] = __float2bfloat16(v);
    }
}

// ---------------- launch ------------------------------------------------
extern "C" void kernel_launch(void* const* d_in, const int* in_sizes, int n_in,
                              void* d_out, int out_size, void* d_ws, size_t ws_size,
                              hipStream_t stream) {
    const float* sf     = (const float*)d_in[0];
    const float* time_w = (const float*)d_in[1];
    const float* time_b = (const float*)d_in[2];
    const float* wq  = (const float*)d_in[3];
    const float* bq  = (const float*)d_in[4];
    const float* wk  = (const float*)d_in[5];
    const float* bk  = (const float*)d_in[6];
    const float* wv  = (const float*)d_in[7];
    const float* bv  = (const float*)d_in[8];
    const float* f1w = (const float*)d_in[9];
    const float* f1b = (const float*)d_in[10];
    const float* f2w = (const float*)d_in[11];
    const float* f2b = (const float*)d_in[12];
    const float* times0 = (const float*)d_in[13];
    const float* nbrt0  = (const float*)d_in[14];
    const float* times1 = (const float*)d_in[15];
    const float* nbrt1  = (const float*)d_in[16];
    const float* edge0  = (const float*)d_in[17];
    const float* edge1  = (const float*)d_in[18];
    const int* nids0 = (const int*)d_in[19];
    const int* nbr0  = (const int*)d_in[20];
    const int* nbr1  = (const int*)d_in[21];
    const int* g2l   = (const int*)d_in[22];
    const void* mask0 = d_in[23];
    const void* mask1 = d_in[24];
    float* z = (float*)d_out;

    char* wsp = (char*)d_ws;
    size_t off = 0;
    auto alloc = [&](size_t bytes) -> void* {
        void* p = wsp + off;
        off += (bytes + 255) & ~(size_t)255;
        return p;
    };
    int*   mode   = (int*)alloc(4);
    bf16*  wkvT   = (bf16*)alloc((size_t)2 * NPADR * KP * sizeof(bf16));
    float* biaskv = (float*)alloc(2 * 352 * sizeof(float));
    bf16*  wqT    = (bf16*)alloc((size_t)2 * 192 * QS * sizeof(bf16));
    float* biasq  = (float*)alloc(2 * 176 * sizeof(float));
    bf16*  f1T    = (bf16*)alloc((size_t)2 * 192 * F1S * sizeof(bf16));
    float* biasf1 = (float*)alloc(2 * 176 * sizeof(float));
    bf16*  f2T    = (bf16*)alloc((size_t)2 * 192 * HS * sizeof(bf16));
    float* biasf2 = (float*)alloc(2 * 176 * sizeof(float));
    bf16*  qin1 = (bf16*)alloc((size_t)N1C * QS * sizeof(bf16));
    bf16*  qin0 = (bf16*)alloc((size_t)N0C * QS * sizeof(bf16));
    float* q1 = (float*)alloc((size_t)N1C * DD * sizeof(float));
    float* q0 = (float*)alloc((size_t)N0C * DD * sizeof(float));
    bf16*  f1in1 = (bf16*)alloc((size_t)N1C * F1S * sizeof(bf16));
    bf16*  f1in0 = (bf16*)alloc((size_t)N0C * F1S * sizeof(bf16));
    bf16*  h1 = (bf16*)alloc((size_t)N1C * HS * sizeof(bf16));
    bf16*  h0 = (bf16*)alloc((size_t)N0C * HS * sizeof(bf16));
    bf16*  kv1 = (bf16*)alloc((size_t)M1 * NKV * sizeof(bf16));
    bf16*  kv0 = (bf16*)alloc((size_t)M0 * NKV * sizeof(bf16));
    size_t avail = (ws_size > off) ? (ws_size - off) : 0;
    size_t rows_fit = avail / ((size_t)KP * sizeof(bf16));
    // chunk multiple of 640 = lcm(nodes:20, m-tile:128); cap at CHUNK_ROWS for L3 residency
    long chunkRows = (long)((rows_fit / 640) * 640);
    if (chunkRows > CHUNK_ROWS) chunkRows = CHUNK_ROWS;
    if (chunkRows < 640) chunkRows = 640;   // minimal fallback
    bf16* Achunk = (bf16*)(wsp + off);

    // one mega-prep launch (wkvT + wq/f1/f2 transposes + mask probe)
    prep_mega_kernel<<<2689, 256, 0, stream>>>(
        wk, wv, bk, bv, wq, bq, f1w, f1b, f2w, f2b,
        wkvT, biaskv, wqT, biasq, f1T, biasf1, f2T, biasf2,
        (const unsigned*)mask1, (N1C * KK) / 4, mode);

    // independent q paths first (fills pipeline, off layer-0 critical chain)
    stage_qin_kernel<<<N1C / 4, 256, 0, stream>>>(sf, nbr0, time_b, qin1);
    stage_qin_kernel<<<N0C / 4, 256, 0, stream>>>(sf, nids0, time_b, qin0);
    gemm176_kernel<QS, false, 1><<<N1C / BM, 256, 0, stream>>>(
        qin1, wqT + (size_t)192 * QS, biasq + 176, q1, DD, nullptr, nullptr);
    gemm176_kernel<QS, false, 1><<<N0C / BM, 256, 0, stream>>>(
        qin0, wqT, biasq, q0, DD, nullptr, nullptr);

    // ---- layer 1: L3-blocked stage -> gemm -> attn per chunk ----
    for (long r0 = 0; r0 < M1; r0 += chunkRows) {
        long rows = M1 - r0 < chunkRows ? M1 - r0 : chunkRows;
        stage_kvin_kernel<<<(int)(rows / 4), 256, 0, stream>>>(
            sf, nbr1, edge1, times1, nbrt1, mask1, mode, time_w, time_b,
            nullptr, g2l, 0, (int)r0, Achunk);
        gemm_kv_kernel<<<(int)((rows / BM) * 2), 256, 0, stream>>>(
            Achunk, wkvT + (size_t)NPADR * KP, biaskv + 352,
            kv1 + (size_t)r0 * NKV, (int)(rows / BM));
        attn_kernel<<<(int)(rows / KK), 64, 0, stream>>>(
            q1, kv1, mask1, mode, sf, nbr0, f1in1, (int)(r0 / KK));
    }
    gemm176_kernel<F1S, true, 0><<<N1C / BM, 256, 0, stream>>>(
        f1in1, f1T + (size_t)192 * F1S, biasf1 + 176, h1, HS, nullptr, nullptr);
    gemm176_kernel<HS, false, 2><<<N1C / BM, 256, 0, stream>>>(
        h1, f2T + (size_t)192 * HS, biasf2 + 176, z, DD, nbr0, g2l);

    // ---- layer 0 (single chunk; q0 already done) ----
    for (long r0 = 0; r0 < M0; r0 += chunkRows) {
        long rows = M0 - r0 < chunkRows ? M0 - r0 : chunkRows;
        stage_kvin_kernel<<<(int)(rows / 4), 256, 0, stream>>>(
            sf, nbr0, edge0, times0, nbrt0, mask0, mode, time_w, time_b,
            z, g2l, 1, (int)r0, Achunk);
        gemm_kv_kernel<<<(int)((rows / BM) * 2), 256, 0, stream>>>(
            Achunk, wkvT, biaskv,
            kv0 + (size_t)r0 * NKV, (int)(rows / BM));
        attn_kernel<<<(int)(rows / KK), 64, 0, stream>>>(
            q0, kv0, mask0, mode, sf, nids0, f1in0, (int)(r0 / KK));
    }
    gemm176_kernel<F1S, true, 0><<<N0C / BM, 256, 0, stream>>>(
        f1in0, f1T, biasf1, h0, HS, nullptr, nullptr);
    gemm176_kernel<HS, false, 2><<<N0C / BM, 256, 0, stream>>>(
        h0, f2T, biasf2, z, DD, nids0, g2l);
}

// Round 11
// 509.931 us; speedup vs baseline: 1.1134x; 1.1134x over previous
//
#include <hip/hip_runtime.h>
#include <hip/hip_bf16.h>

typedef __hip_bfloat16 bf16;
typedef __attribute__((ext_vector_type(8))) short short8;
typedef __attribute__((ext_vector_type(4))) float f32x4;

#define DD    172      // D
#define EE    172      // E
#define QIN   272      // D+T
#define KK    20
#define HH    2
#define DHH   86
#define N0C   512
#define N1C   10240
#define M1    204800   // N1*K rows
#define M0    10240    // N0*K rows

// GEMM geometry
#define BM   128
#define BN   176
#define BK   64
#define KP   448       // kv_in padded K (444 -> 448)
#define NKV  344       // kv row stride (k|v)
#define NPADR 384      // wkvT rows per layer
#define QS   320       // qin padded K
#define F1S  384       // f1in padded K
#define HS   192       // h padded K

#define GLOAD(src, dst) __builtin_amdgcn_global_load_lds( \
    (const __attribute__((address_space(1))) unsigned int*)(src), \
    (__attribute__((address_space(3))) unsigned int*)(dst), 16, 0, 0)

__device__ __forceinline__ float bfu2f(unsigned short u) {
    return __uint_as_float(((unsigned)u) << 16);
}

// fast cos: x -> revolutions -> v_fract -> v_cos (verified r7/r8: absmax unchanged)
__device__ __forceinline__ float fastcos(float x) {
    float r = x * 0.15915494309189535f;
    r = __builtin_amdgcn_fractf(r);
    return __builtin_amdgcn_cosf(r);
}

__device__ __forceinline__ unsigned pack2bf(float a, float b) {
    union { bf16 h[2]; unsigned u; } p;
    p.h[0] = __float2bfloat16(a);
    p.h[1] = __float2bfloat16(b);
    return p.u;
}

__device__ __forceinline__ bool get_mask(const void* m, int mode, int idx) {
    if (mode == 1) return ((const unsigned char*)m)[idx] != 0;
    if (mode == 2) return ((const float*)m)[idx] != 0.0f;
    return ((const int*)m)[idx] != 0;
}

// ---------------- mega prep: wkvT + 6 wT jobs + mask probe, one launch ---
// block ranges: [0,1344) wkvT | [1344,1824) wq | [1824,2400) f1 | [2400,2688) f2 | 2688 probe
__global__ void prep_mega_kernel(
    const float* __restrict__ wk, const float* __restrict__ wv,
    const float* __restrict__ bk, const float* __restrict__ bv,
    const float* __restrict__ wq, const float* __restrict__ bq,
    const float* __restrict__ f1w, const float* __restrict__ f1b,
    const float* __restrict__ f2w, const float* __restrict__ f2b,
    bf16* __restrict__ wkvT, float* __restrict__ biaskv,
    bf16* __restrict__ wqT, float* __restrict__ biasq,
    bf16* __restrict__ f1T, float* __restrict__ biasf1,
    bf16* __restrict__ f2T, float* __restrict__ biasf2,
    const unsigned* __restrict__ maskw, int n_ints, int* __restrict__ mode_out) {
    int blk = blockIdx.x;
    if (blk < 1344) {
        size_t i = (size_t)blk * 256 + threadIdx.x;
        size_t tot = (size_t)2 * NPADR * KP;
        if (i < tot) {
            int l = (int)(i / ((size_t)NPADR * KP));
            int rem = (int)(i % ((size_t)NPADR * KP));
            int k = rem / NPADR;
            int n = rem % NPADR;
            float v = 0.f;
            if (k < 444) {
                if (n < DD)          v = wk[((size_t)l * 444 + k) * DD + n];
                else if (n < 2 * DD) v = wv[((size_t)l * 444 + k) * DD + (n - DD)];
            }
            wkvT[((size_t)l * NPADR + n) * KP + k] = __float2bfloat16(v);
            if (i < 2 * 352) {
                int nn = (int)(i % 352), ll = (int)(i / 352);
                biaskv[i] = nn < DD ? bk[ll * DD + nn] : (nn < 2 * DD ? bv[ll * DD + nn - DD] : 0.f);
            }
        }
        return;
    }
    if (blk < 2688) {
        int job;
        const float* W; const float* b; bf16* dstT; float* biasdst; int K, KPdst;
        if (blk < 1824)      { job = blk - 1344; }
        else if (blk < 2400) { job = blk - 1824; }
        else                 { job = blk - 2400; }
        int per = (blk < 1824) ? 240 : (blk < 2400) ? 288 : 144;
        int l = job / per;
        int sub = job % per;
        if (blk < 1824)      { W = wq  + (size_t)l * QIN * DD; b = bq  + (size_t)l * DD; dstT = wqT + (size_t)l * 192 * QS;  biasdst = biasq  + l * 176; K = QIN; KPdst = QS;  }
        else if (blk < 2400) { W = f1w + (size_t)l * 344 * DD; b = f1b + (size_t)l * DD; dstT = f1T + (size_t)l * 192 * F1S; biasdst = biasf1 + l * 176; K = 344; KPdst = F1S; }
        else                 { W = f2w + (size_t)l * DD * DD;  b = f2b + (size_t)l * DD; dstT = f2T + (size_t)l * 192 * HS;  biasdst = biasf2 + l * 176; K = DD;  KPdst = HS;  }
        int i = sub * 256 + threadIdx.x;
        int tot = 192 * KPdst;
        if (i < tot) {
            int n = i / KPdst, k = i % KPdst;
            float v = (n < DD && k < K) ? W[(size_t)k * DD + n] : 0.f;
            dstT[(size_t)n * KPdst + k] = __float2bfloat16(v);
        }
        if (i < 176) biasdst[i] = (i < DD) ? b[i] : 0.f;
        return;
    }
    // probe job (1 block)
    __shared__ int c_other, c_float;
    if (threadIdx.x == 0) { c_other = 0; c_float = 0; }
    __syncthreads();
    int lo = 0, lf = 0;
    for (int i = threadIdx.x; i < n_ints; i += blockDim.x) {
        unsigned v = maskw[i];
        if (v == 0x3F800000u) lf++;
        else if (v > 1u) lo++;
    }
    if (lo) atomicAdd(&c_other, lo);
    if (lf) atomicAdd(&c_float, lf);
    __syncthreads();
    if (threadIdx.x == 0) {
        int mode = 0;
        if (c_float > 0) mode = 2;
        else if (c_other > 0) mode = 1;
        *mode_out = mode;
    }
}

// ---------------- kv_in staging: [nbr_feat | edge | cos(dt*w+b) | 0pad] --
// pair-per-lane: cols (2l, 2l+1) — region boundaries (172/344/444) are even,
// so a pair never straddles. float2 loads, 4B packed-bf16 stores, stride-1.
__global__ __launch_bounds__(256) void stage_kvin_kernel(
    const float* __restrict__ sf, const int* __restrict__ nbrs,
    const float* __restrict__ edge, const float* __restrict__ times,
    const float* __restrict__ nbrt,
    const void* __restrict__ mask, const int* __restrict__ mode_p,
    const float* __restrict__ time_w, const float* __restrict__ time_b,
    const float* __restrict__ zbuf, const int* __restrict__ g2l, int use_z,
    int row0, bf16* __restrict__ out) {
    int wave = threadIdx.x >> 6, lane = threadIdx.x & 63;
    int lrow = blockIdx.x * 4 + wave;
    int row = row0 + lrow;
    int mode = *mode_p;
    int g = nbrs[row];
    bool mk = get_mask(mask, mode, row);
    float dt = mk ? (times[row / KK] - nbrt[row]) : 0.f;
    const float* src = (use_z && mk) ? (zbuf + (size_t)g2l[g] * DD)
                                     : (sf + (size_t)g * DD);
    const float* erow = edge + (size_t)row * EE;
    bf16* orow = out + (size_t)lrow * KP;
#pragma unroll
    for (int i2 = 0; i2 < KP; i2 += 128) {
        int col = i2 + 2 * lane;
        if (col >= KP) break;
        float v0, v1;
        if (col < DD) {
            float2 u = *(const float2*)(src + col);
            v0 = u.x; v1 = u.y;
        } else if (col < DD + EE) {
            float2 u = *(const float2*)(erow + (col - DD));
            v0 = u.x; v1 = u.y;
        } else if (col < 444) {
            int t = col - DD - EE;
            v0 = fastcos(dt * time_w[t] + time_b[t]);
            v1 = fastcos(dt * time_w[t + 1] + time_b[t + 1]);
        } else {
            v0 = 0.f; v1 = 0.f;
        }
        *(unsigned*)(orow + col) = pack2bf(v0, v1);
    }
}

// ---------------- q_in staging: [feat | cos(time_b) | 0pad] -------------
__global__ __launch_bounds__(256) void stage_qin_kernel(
    const float* __restrict__ sf, const int* __restrict__ idx,
    const float* __restrict__ time_b, bf16* __restrict__ out) {
    int wave = threadIdx.x >> 6, lane = threadIdx.x & 63;
    int row = blockIdx.x * 4 + wave;
    const float* src = sf + (size_t)idx[row] * DD;
    bf16* orow = out + (size_t)row * QS;
#pragma unroll
    for (int i2 = 0; i2 < QS; i2 += 128) {
        int col = i2 + 2 * lane;
        if (col >= QS) break;
        float v0, v1;
        if (col < DD) {
            float2 u = *(const float2*)(src + col);
            v0 = u.x; v1 = u.y;
        } else if (col < QIN) {
            v0 = fastcos(time_b[col - DD]);
            v1 = fastcos(time_b[col - DD + 1]);
        } else {
            v0 = 0.f; v1 = 0.f;
        }
        *(unsigned*)(orow + col) = pack2bf(v0, v1);
    }
}

// ---------------- MFMA GEMM (kv), single-pass BN=352 --------------------
// 512 threads = 8 waves (4M x 2N); per wave 32 rows x 176 cols (acc 2x11,
// same shape as proven kernel). A staged ONCE per m-tile (no n-tile re-read).
// LDS: As[128][64] 16K + Bs[384][64] 48K = 64K -> 2 blocks/CU = 16 waves/CU.
__global__ __launch_bounds__(512) void gemm_kv_kernel(
    const bf16* __restrict__ A, const bf16* __restrict__ BT,
    const float* __restrict__ bias, bf16* __restrict__ kvout) {
    __shared__ __align__(16) char smem[65536];
    int tid = threadIdx.x;
    int lane = tid & 63;
    int wave = tid >> 6;
    int ml = lane & 15;
    int kg = lane >> 4;
    int wm = wave >> 1;     // 0..3 -> 32-row group
    int wn = wave & 1;      // 0..1 -> 176-col half
    int m0 = blockIdx.x * BM;

    f32x4 acc[2][11];
#pragma unroll
    for (int mg = 0; mg < 2; ++mg)
#pragma unroll
        for (int fn = 0; fn < 11; ++fn)
            acc[mg][fn] = (f32x4){0.f, 0.f, 0.f, 0.f};

    for (int kk = 0; kk < KP; kk += BK) {
        // stage A: 1024 chunks over 512 threads (2 iters)
#pragma unroll
        for (int it = 0; it < 2; ++it) {
            int c = it * 512 + tid;
            int row = c >> 3, slot = c & 7;
            int sslot = slot ^ (row & 7);
            const bf16* src = A + (size_t)(m0 + row) * KP + kk + sslot * 8;
            GLOAD(src, smem + (size_t)(it * 512 + wave * 64) * 16);
        }
        // stage B: 384 rows x 8 slots = 3072 chunks (6 iters)
#pragma unroll
        for (int it = 0; it < 6; ++it) {
            int c = it * 512 + tid;
            int row = c >> 3, slot = c & 7;
            int sslot = slot ^ (row & 7);
            const bf16* src = BT + (size_t)row * KP + kk + sslot * 8;
            GLOAD(src, smem + 16384 + (size_t)(it * 512 + wave * 64) * 16);
        }
        __syncthreads();
#pragma unroll
        for (int half = 0; half < 2; ++half) {
            int kc = kg + half * 4;
            short8 a[2], b[11];
#pragma unroll
            for (int mg = 0; mg < 2; ++mg) {
                int r = wm * 32 + mg * 16 + ml;
                a[mg] = *(const short8*)(smem + r * 128 + ((kc ^ (r & 7)) << 4));
            }
#pragma unroll
            for (int fn = 0; fn < 11; ++fn) {
                int r = wn * 176 + fn * 16 + ml;
                b[fn] = *(const short8*)(smem + 16384 + r * 128 + ((kc ^ (r & 7)) << 4));
            }
#pragma unroll
            for (int mg = 0; mg < 2; ++mg)
#pragma unroll
                for (int fn = 0; fn < 11; ++fn)
                    acc[mg][fn] = __builtin_amdgcn_mfma_f32_16x16x32_bf16(a[mg], b[fn], acc[mg][fn], 0, 0, 0);
        }
        __syncthreads();
    }
#pragma unroll
    for (int mg = 0; mg < 2; ++mg)
#pragma unroll
        for (int fn = 0; fn < 11; ++fn) {
            int col = wn * 176 + fn * 16 + ml;
            if (col < NKV) {
                float bb = bias[col];
#pragma unroll
                for (int r4 = 0; r4 < 4; ++r4) {
                    int row = m0 + wm * 32 + mg * 16 + kg * 4 + r4;
                    kvout[(size_t)row * NKV + col] = __float2bfloat16(acc[mg][fn][r4] + bb);
                }
            }
        }
}

// ---------------- generic 176-col MFMA GEMM -----------------------------
// OMODE: 0 = bf16 dense (stride ostride, zero pad cols 176..ostride),
//        1 = fp32 dense (cols < 172), 2 = fp32 scatter rows via g2l[idx[row]]
template<int KP_, bool RELU, int OMODE>
__global__ __launch_bounds__(256) void gemm176_kernel(
    const bf16* __restrict__ A, const bf16* __restrict__ BT,
    const float* __restrict__ bias, void* __restrict__ outp, int ostride,
    const int* __restrict__ idx, const int* __restrict__ g2l) {
    int m0 = blockIdx.x * BM;
    __shared__ bf16 As[BM][BK];
    __shared__ bf16 Bs[192][BK];
    int tid = threadIdx.x;
    int lane = tid & 63;
    int wave = tid >> 6;
    int ml = lane & 15;
    int kg = lane >> 4;

    f32x4 acc[2][11];
#pragma unroll
    for (int mg = 0; mg < 2; ++mg)
#pragma unroll
        for (int fn = 0; fn < 11; ++fn)
            acc[mg][fn] = (f32x4){0.f, 0.f, 0.f, 0.f};

    for (int kk = 0; kk < KP_; kk += BK) {
        int c0 = tid;
#pragma unroll
        for (int it = 0; it < 4; ++it) {
            int c = it * 256 + c0;
            int row = c >> 3, slot = c & 7;
            int sslot = slot ^ (row & 7);
            const bf16* src = A + (size_t)(m0 + row) * KP_ + kk + sslot * 8;
            GLOAD(src, ((char*)As) + (size_t)(it * 256 + wave * 64) * 16);
        }
#pragma unroll
        for (int it = 0; it < 6; ++it) {
            int c = it * 256 + c0;
            int row = c >> 3, slot = c & 7;
            int sslot = slot ^ (row & 7);
            const bf16* src = BT + (size_t)row * KP_ + kk + sslot * 8;
            GLOAD(src, ((char*)Bs) + (size_t)(it * 256 + wave * 64) * 16);
        }
        __syncthreads();
#pragma unroll
        for (int half = 0; half < 2; ++half) {
            int kc = kg + half * 4;
            short8 a[2], b[11];
#pragma unroll
            for (int mg = 0; mg < 2; ++mg) {
                int r = wave * 32 + mg * 16 + ml;
                a[mg] = *(const short8*)(((const char*)As) + (size_t)r * 128 + ((size_t)(kc ^ (r & 7)) << 4));
            }
#pragma unroll
            for (int fn = 0; fn < 11; ++fn) {
                int r = fn * 16 + ml;
                b[fn] = *(const short8*)(((const char*)Bs) + (size_t)r * 128 + ((size_t)(kc ^ (r & 7)) << 4));
            }
#pragma unroll
            for (int mg = 0; mg < 2; ++mg)
#pragma unroll
                for (int fn = 0; fn < 11; ++fn)
                    acc[mg][fn] = __builtin_amdgcn_mfma_f32_16x16x32_bf16(a[mg], b[fn], acc[mg][fn], 0, 0, 0);
        }
        __syncthreads();
    }
#pragma unroll
    for (int mg = 0; mg < 2; ++mg)
#pragma unroll
        for (int fn = 0; fn < 11; ++fn) {
            int col = fn * 16 + ml;
            float bb = bias[col];
#pragma unroll
            for (int r4 = 0; r4 < 4; ++r4) {
                int row = m0 + wave * 32 + mg * 16 + kg * 4 + r4;
                float v = acc[mg][fn][r4] + bb;
                if (RELU) v = fmaxf(v, 0.f);
                if (OMODE == 0) {
                    ((bf16*)outp)[(size_t)row * ostride + col] = __float2bfloat16(v);
                } else if (OMODE == 1) {
                    if (col < DD) ((float*)outp)[(size_t)row * ostride + col] = v;
                } else {
                    if (col < DD) {
                        int zr = g2l[idx[row]];
                        ((float*)outp)[(size_t)zr * DD + col] = v;
                    }
                }
            }
        }
    if (OMODE == 0 && ostride > 176) {
        int row = tid >> 1, half = tid & 1;
        short8 zz = (short8){0, 0, 0, 0, 0, 0, 0, 0};
        *(short8*)&((bf16*)outp)[(size_t)(m0 + row) * ostride + 176 + half * 8] = zz;
    }
}

// ---------------- attention over K=20 neighbors (kv packed [row][344]) --
#define ASTR 360
__global__ __launch_bounds__(64) void attn_kernel(
    const float* __restrict__ q, const bf16* __restrict__ kv,
    const void* __restrict__ mask, const int* __restrict__ mode_p,
    const float* __restrict__ sf, const int* __restrict__ idx,
    bf16* __restrict__ f1out) {
    int node = blockIdx.x;
    int lane = threadIdx.x;
    __shared__ unsigned short kvls[KK][ASTR];
    __shared__ float qs[DD];
    __shared__ float sc[HH][KK];
    __shared__ float aw[HH][KK];
    int mode = *mode_p;
    const unsigned short* kvg = (const unsigned short*)(kv + (size_t)node * KK * NKV);
    for (int c = lane; c < 860; c += 64) {          // 20*344/8 = 860 chunks
        int r = c / 43, cc = c % 43;
        *(short8*)&kvls[r][cc * 8] = *(const short8*)(kvg + (size_t)c * 8);
    }
    for (int i = lane; i < DD; i += 64) qs[i] = q[(size_t)node * DD + i];
    __syncthreads();
    if (lane < HH * KK) {
        int h = lane / KK, kx = lane % KK;
        bool mk = get_mask(mask, mode, node * KK + kx);
        float s = 0.f;
        const unsigned short* kr = &kvls[kx][h * DHH];
        for (int d = 0; d < DHH; d++) s += qs[h * DHH + d] * bfu2f(kr[d]);
        sc[h][kx] = mk ? s * 0.10783277320f : -3.0e38f;
    }
    __syncthreads();
    if (lane < HH) {
        int h = lane;
        float m = -3.0e38f;
        for (int k2 = 0; k2 < KK; k2++) m = fmaxf(m, sc[h][k2]);
        float den = 0.f;
        for (int k2 = 0; k2 < KK; k2++) {
            float e = (sc[h][k2] <= -1e37f) ? 0.f : expf(sc[h][k2] - m);
            sc[h][k2] = e;
            den += e;
        }
        float inv = (den > 0.f) ? 1.f / den : 0.f;
        for (int k2 = 0; k2 < KK; k2++) aw[h][k2] = sc[h][k2] * inv;
    }
    __syncthreads();
    bf16* orow = f1out + (size_t)node * F1S;
    for (int jj = lane; jj < DD; jj += 64) {
        int h = jj / DHH;
        float s = 0.f;
        for (int k2 = 0; k2 < KK; k2++)
            s += aw[h][k2] * bfu2f(kvls[k2][DD + jj]);
        orow[jj] = __float2bfloat16(s);
    }
    const float* src = sf + (size_t)idx[node] * DD;
    for (int c = lane; c < F1S - DD; c += 64) {     // cols 172..383: nf then 0
        float v = (c < DD) ? src[c] : 0.f;
        orow[DD + c] = __float2bfloat16(v);
    }
}

// ---------------- launch ------------------------------------------------
extern "C" void kernel_launch(void* const* d_in, const int* in_sizes, int n_in,
                              void* d_out, int out_size, void* d_ws, size_t ws_size,
                              hipStream_t stream) {
    const float* sf     = (const float*)d_in[0];
    const float* time_w = (const float*)d_in[1];
    const float* time_b = (const float*)d_in[2];
    const float* wq  = (const float*)d_in[3];
    const float* bq  = (const float*)d_in[4];
    const float* wk  = (const float*)d_in[5];
    const float* bk  = (const float*)d_in[6];
    const float* wv  = (const float*)d_in[7];
    const float* bv  = (const float*)d_in[8];
    const float* f1w = (const float*)d_in[9];
    const float* f1b = (const float*)d_in[10];
    const float* f2w = (const float*)d_in[11];
    const float* f2b = (const float*)d_in[12];
    const float* times0 = (const float*)d_in[13];
    const float* nbrt0  = (const float*)d_in[14];
    const float* times1 = (const float*)d_in[15];
    const float* nbrt1  = (const float*)d_in[16];
    const float* edge0  = (const float*)d_in[17];
    const float* edge1  = (const float*)d_in[18];
    const int* nids0 = (const int*)d_in[19];
    const int* nbr0  = (const int*)d_in[20];
    const int* nbr1  = (const int*)d_in[21];
    const int* g2l   = (const int*)d_in[22];
    const void* mask0 = d_in[23];
    const void* mask1 = d_in[24];
    float* z = (float*)d_out;

    char* wsp = (char*)d_ws;
    size_t off = 0;
    auto alloc = [&](size_t bytes) -> void* {
        void* p = wsp + off;
        off += (bytes + 255) & ~(size_t)255;
        return p;
    };
    int*   mode   = (int*)alloc(4);
    bf16*  wkvT   = (bf16*)alloc((size_t)2 * NPADR * KP * sizeof(bf16));
    float* biaskv = (float*)alloc(2 * 352 * sizeof(float));
    bf16*  wqT    = (bf16*)alloc((size_t)2 * 192 * QS * sizeof(bf16));
    float* biasq  = (float*)alloc(2 * 176 * sizeof(float));
    bf16*  f1T    = (bf16*)alloc((size_t)2 * 192 * F1S * sizeof(bf16));
    float* biasf1 = (float*)alloc(2 * 176 * sizeof(float));
    bf16*  f2T    = (bf16*)alloc((size_t)2 * 192 * HS * sizeof(bf16));
    float* biasf2 = (float*)alloc(2 * 176 * sizeof(float));
    bf16*  qin1 = (bf16*)alloc((size_t)N1C * QS * sizeof(bf16));
    bf16*  qin0 = (bf16*)alloc((size_t)N0C * QS * sizeof(bf16));
    float* q1 = (float*)alloc((size_t)N1C * DD * sizeof(float));
    float* q0 = (float*)alloc((size_t)N0C * DD * sizeof(float));
    bf16*  f1in1 = (bf16*)alloc((size_t)N1C * F1S * sizeof(bf16));
    bf16*  f1in0 = (bf16*)alloc((size_t)N0C * F1S * sizeof(bf16));
    bf16*  h1 = (bf16*)alloc((size_t)N1C * HS * sizeof(bf16));
    bf16*  h0 = (bf16*)alloc((size_t)N0C * HS * sizeof(bf16));
    bf16*  kv1 = (bf16*)alloc((size_t)M1 * NKV * sizeof(bf16));
    bf16*  kv0 = (bf16*)alloc((size_t)M0 * NKV * sizeof(bf16));
    size_t avail = (ws_size > off) ? (ws_size - off) : 0;
    size_t rows_fit = avail / ((size_t)KP * sizeof(bf16));
    long chunkRows = (long)((rows_fit / BM) * BM);
    if (chunkRows > M1) chunkRows = M1;
    if (chunkRows < BM) chunkRows = BM;
    bf16* Achunk = (bf16*)(wsp + off);

    // one mega-prep launch (wkvT + wq/f1/f2 transposes + mask probe)
    prep_mega_kernel<<<2689, 256, 0, stream>>>(
        wk, wv, bk, bv, wq, bq, f1w, f1b, f2w, f2b,
        wkvT, biaskv, wqT, biasq, f1T, biasf1, f2T, biasf2,
        (const unsigned*)mask1, (N1C * KK) / 4, mode);

    // independent q paths first (fills pipeline, off layer-0 critical chain)
    stage_qin_kernel<<<N1C / 4, 256, 0, stream>>>(sf, nbr0, time_b, qin1);
    stage_qin_kernel<<<N0C / 4, 256, 0, stream>>>(sf, nids0, time_b, qin0);
    gemm176_kernel<QS, false, 1><<<N1C / BM, 256, 0, stream>>>(
        qin1, wqT + (size_t)192 * QS, biasq + 176, q1, DD, nullptr, nullptr);
    gemm176_kernel<QS, false, 1><<<N0C / BM, 256, 0, stream>>>(
        qin0, wqT, biasq, q0, DD, nullptr, nullptr);

    // ---- layer 1 ----
    for (long r0 = 0; r0 < M1; r0 += chunkRows) {
        long rows = M1 - r0 < chunkRows ? M1 - r0 : chunkRows;
        stage_kvin_kernel<<<(int)(rows / 4), 256, 0, stream>>>(
            sf, nbr1, edge1, times1, nbrt1, mask1, mode, time_w, time_b,
            nullptr, g2l, 0, (int)r0, Achunk);
        gemm_kv_kernel<<<(int)(rows / BM), 512, 0, stream>>>(
            Achunk, wkvT + (size_t)NPADR * KP, biaskv + 352,
            kv1 + (size_t)r0 * NKV);
    }
    attn_kernel<<<N1C, 64, 0, stream>>>(q1, kv1, mask1, mode, sf, nbr0, f1in1);
    gemm176_kernel<F1S, true, 0><<<N1C / BM, 256, 0, stream>>>(
        f1in1, f1T + (size_t)192 * F1S, biasf1 + 176, h1, HS, nullptr, nullptr);
    gemm176_kernel<HS, false, 2><<<N1C / BM, 256, 0, stream>>>(
        h1, f2T + (size_t)192 * HS, biasf2 + 176, z, DD, nbr0, g2l);

    // ---- layer 0 (q0 already done) ----
    for (long r0 = 0; r0 < M0; r0 += chunkRows) {
        long rows = M0 - r0 < chunkRows ? M0 - r0 : chunkRows;
        stage_kvin_kernel<<<(int)(rows / 4), 256, 0, stream>>>(
            sf, nbr0, edge0, times0, nbrt0, mask0, mode, time_w, time_b,
            z, g2l, 1, (int)r0, Achunk);
        gemm_kv_kernel<<<(int)(rows / BM), 512, 0, stream>>>(
            Achunk, wkvT, biaskv,
            kv0 + (size_t)r0 * NKV);
    }
    attn_kernel<<<N0C, 64, 0, stream>>>(q0, kv0, mask0, mode, sf, nids0, f1in0);
    gemm176_kernel<F1S, true, 0><<<N0C / BM, 256, 0, stream>>>(
        f1in0, f1T, biasf1, h0, HS, nullptr, nullptr);
    gemm176_kernel<HS, false, 2><<<N0C / BM, 256, 0, stream>>>(
        h0, f2T, biasf2, z, DD, nids0, g2l);
}

// Round 12
// 486.551 us; speedup vs baseline: 1.1669x; 1.0481x over previous
//
#include <hip/hip_runtime.h>
#include <hip/hip_bf16.h>

typedef __hip_bfloat16 bf16;
typedef __attribute__((ext_vector_type(8))) short short8;
typedef __attribute__((ext_vector_type(4))) float f32x4;

#define DD    172      // D
#define EE    172      // E
#define QIN   272      // D+T
#define KK    20
#define HH    2
#define DHH   86
#define N0C   512
#define N1C   10240
#define M1    204800   // N1*K rows
#define M0    10240    // N0*K rows

// GEMM geometry
#define BM   128
#define BN   176
#define BK   64
#define KP   448       // kv_in padded K (444 -> 448)
#define NKV  344       // kv row stride (k|v)
#define NPADR 384      // wkvT rows per layer
#define QS   320       // qin padded K
#define F1S  384       // f1in padded K
#define HS   192       // h padded K

#define GLOAD(src, dst) __builtin_amdgcn_global_load_lds( \
    (const __attribute__((address_space(1))) unsigned int*)(src), \
    (__attribute__((address_space(3))) unsigned int*)(dst), 16, 0, 0)

__device__ __forceinline__ float bfu2f(unsigned short u) {
    return __uint_as_float(((unsigned)u) << 16);
}

// fast cos: x -> revolutions -> v_fract -> v_cos (verified r7/r8: absmax unchanged)
__device__ __forceinline__ float fastcos(float x) {
    float r = x * 0.15915494309189535f;
    r = __builtin_amdgcn_fractf(r);
    return __builtin_amdgcn_cosf(r);
}

__device__ __forceinline__ unsigned pack2bf(float a, float b) {
    union { bf16 h[2]; unsigned u; } p;
    p.h[0] = __float2bfloat16(a);
    p.h[1] = __float2bfloat16(b);
    return p.u;
}

__device__ __forceinline__ bool get_mask(const void* m, int mode, int idx) {
    if (mode == 1) return ((const unsigned char*)m)[idx] != 0;
    if (mode == 2) return ((const float*)m)[idx] != 0.0f;
    return ((const int*)m)[idx] != 0;
}

// ---------------- mega prep: wkvT + 6 wT jobs + mask probe, one launch ---
// block ranges: [0,1344) wkvT | [1344,1824) wq | [1824,2400) f1 | [2400,2688) f2 | 2688 probe
__global__ void prep_mega_kernel(
    const float* __restrict__ wk, const float* __restrict__ wv,
    const float* __restrict__ bk, const float* __restrict__ bv,
    const float* __restrict__ wq, const float* __restrict__ bq,
    const float* __restrict__ f1w, const float* __restrict__ f1b,
    const float* __restrict__ f2w, const float* __restrict__ f2b,
    bf16* __restrict__ wkvT, float* __restrict__ biaskv,
    bf16* __restrict__ wqT, float* __restrict__ biasq,
    bf16* __restrict__ f1T, float* __restrict__ biasf1,
    bf16* __restrict__ f2T, float* __restrict__ biasf2,
    const unsigned* __restrict__ maskw, int n_ints, int* __restrict__ mode_out) {
    int blk = blockIdx.x;
    if (blk < 1344) {
        size_t i = (size_t)blk * 256 + threadIdx.x;
        size_t tot = (size_t)2 * NPADR * KP;
        if (i < tot) {
            int l = (int)(i / ((size_t)NPADR * KP));
            int rem = (int)(i % ((size_t)NPADR * KP));
            int k = rem / NPADR;
            int n = rem % NPADR;
            float v = 0.f;
            if (k < 444) {
                if (n < DD)          v = wk[((size_t)l * 444 + k) * DD + n];
                else if (n < 2 * DD) v = wv[((size_t)l * 444 + k) * DD + (n - DD)];
            }
            wkvT[((size_t)l * NPADR + n) * KP + k] = __float2bfloat16(v);
            if (i < 2 * 352) {
                int nn = (int)(i % 352), ll = (int)(i / 352);
                biaskv[i] = nn < DD ? bk[ll * DD + nn] : (nn < 2 * DD ? bv[ll * DD + nn - DD] : 0.f);
            }
        }
        return;
    }
    if (blk < 2688) {
        int job;
        const float* W; const float* b; bf16* dstT; float* biasdst; int K, KPdst;
        if (blk < 1824)      { job = blk - 1344; }
        else if (blk < 2400) { job = blk - 1824; }
        else                 { job = blk - 2400; }
        int per = (blk < 1824) ? 240 : (blk < 2400) ? 288 : 144;
        int l = job / per;
        int sub = job % per;
        if (blk < 1824)      { W = wq  + (size_t)l * QIN * DD; b = bq  + (size_t)l * DD; dstT = wqT + (size_t)l * 192 * QS;  biasdst = biasq  + l * 176; K = QIN; KPdst = QS;  }
        else if (blk < 2400) { W = f1w + (size_t)l * 344 * DD; b = f1b + (size_t)l * DD; dstT = f1T + (size_t)l * 192 * F1S; biasdst = biasf1 + l * 176; K = 344; KPdst = F1S; }
        else                 { W = f2w + (size_t)l * DD * DD;  b = f2b + (size_t)l * DD; dstT = f2T + (size_t)l * 192 * HS;  biasdst = biasf2 + l * 176; K = DD;  KPdst = HS;  }
        int i = sub * 256 + threadIdx.x;
        int tot = 192 * KPdst;
        if (i < tot) {
            int n = i / KPdst, k = i % KPdst;
            float v = (n < DD && k < K) ? W[(size_t)k * DD + n] : 0.f;
            dstT[(size_t)n * KPdst + k] = __float2bfloat16(v);
        }
        if (i < 176) biasdst[i] = (i < DD) ? b[i] : 0.f;
        return;
    }
    // probe job (1 block)
    __shared__ int c_other, c_float;
    if (threadIdx.x == 0) { c_other = 0; c_float = 0; }
    __syncthreads();
    int lo = 0, lf = 0;
    for (int i = threadIdx.x; i < n_ints; i += blockDim.x) {
        unsigned v = maskw[i];
        if (v == 0x3F800000u) lf++;
        else if (v > 1u) lo++;
    }
    if (lo) atomicAdd(&c_other, lo);
    if (lf) atomicAdd(&c_float, lf);
    __syncthreads();
    if (threadIdx.x == 0) {
        int mode = 0;
        if (c_float > 0) mode = 2;
        else if (c_other > 0) mode = 1;
        *mode_out = mode;
    }
}

// ---------------- kv_in staging: [nbr_feat | edge | cos(dt*w+b) | 0pad] --
// pair-per-lane: cols (2l, 2l+1) — region boundaries (172/344/444) are even,
// so a pair never straddles. float2 loads, 4B packed-bf16 stores, stride-1.
__global__ __launch_bounds__(256) void stage_kvin_kernel(
    const float* __restrict__ sf, const int* __restrict__ nbrs,
    const float* __restrict__ edge, const float* __restrict__ times,
    const float* __restrict__ nbrt,
    const void* __restrict__ mask, const int* __restrict__ mode_p,
    const float* __restrict__ time_w, const float* __restrict__ time_b,
    const float* __restrict__ zbuf, const int* __restrict__ g2l, int use_z,
    int row0, bf16* __restrict__ out) {
    int wave = threadIdx.x >> 6, lane = threadIdx.x & 63;
    int lrow = blockIdx.x * 4 + wave;
    int row = row0 + lrow;
    int mode = *mode_p;
    int g = nbrs[row];
    bool mk = get_mask(mask, mode, row);
    float dt = mk ? (times[row / KK] - nbrt[row]) : 0.f;
    const float* src = (use_z && mk) ? (zbuf + (size_t)g2l[g] * DD)
                                     : (sf + (size_t)g * DD);
    const float* erow = edge + (size_t)row * EE;
    bf16* orow = out + (size_t)lrow * KP;
#pragma unroll
    for (int i2 = 0; i2 < KP; i2 += 128) {
        int col = i2 + 2 * lane;
        if (col >= KP) break;
        float v0, v1;
        if (col < DD) {
            float2 u = *(const float2*)(src + col);
            v0 = u.x; v1 = u.y;
        } else if (col < DD + EE) {
            float2 u = *(const float2*)(erow + (col - DD));
            v0 = u.x; v1 = u.y;
        } else if (col < 444) {
            int t = col - DD - EE;
            v0 = fastcos(dt * time_w[t] + time_b[t]);
            v1 = fastcos(dt * time_w[t + 1] + time_b[t + 1]);
        } else {
            v0 = 0.f; v1 = 0.f;
        }
        *(unsigned*)(orow + col) = pack2bf(v0, v1);
    }
}

// ---------------- q_in staging: [feat | cos(time_b) | 0pad] -------------
__global__ __launch_bounds__(256) void stage_qin_kernel(
    const float* __restrict__ sf, const int* __restrict__ idx,
    const float* __restrict__ time_b, bf16* __restrict__ out) {
    int wave = threadIdx.x >> 6, lane = threadIdx.x & 63;
    int row = blockIdx.x * 4 + wave;
    const float* src = sf + (size_t)idx[row] * DD;
    bf16* orow = out + (size_t)row * QS;
#pragma unroll
    for (int i2 = 0; i2 < QS; i2 += 128) {
        int col = i2 + 2 * lane;
        if (col >= QS) break;
        float v0, v1;
        if (col < DD) {
            float2 u = *(const float2*)(src + col);
            v0 = u.x; v1 = u.y;
        } else if (col < QIN) {
            v0 = fastcos(time_b[col - DD]);
            v1 = fastcos(time_b[col - DD + 1]);
        } else {
            v0 = 0.f; v1 = 0.f;
        }
        *(unsigned*)(orow + col) = pack2bf(v0, v1);
    }
}

// ---------------- MFMA GEMM (kv): kv[m][0:344] = A @ wkvT^T + bias ------
// r9-proven: 2 n-tiles, 256 threads, XCD-paired (blocks b, b+8 same XCD
// under round-robin dispatch handle the same m-tile -> A tile L2-shared).
__global__ __launch_bounds__(256) void gemm_kv_kernel(
    const bf16* __restrict__ A, const bf16* __restrict__ BT,
    const float* __restrict__ bias, bf16* __restrict__ kvout, int Mtiles) {
    int bid = blockIdx.x;
    int mt, nt;
    if ((Mtiles & 7) == 0) {
        nt = (bid >> 3) & 1;
        mt = (bid & 7) + ((bid >> 4) << 3);
    } else {
        mt = bid % Mtiles;
        nt = bid / Mtiles;
    }
    int m0 = mt * BM;
    int n0 = nt * BN;
    __shared__ bf16 As[BM][BK];
    __shared__ bf16 Bs[192][BK];
    int tid = threadIdx.x;
    int lane = tid & 63;
    int wave = tid >> 6;
    int ml = lane & 15;
    int kg = lane >> 4;

    f32x4 acc[2][11];
#pragma unroll
    for (int mg = 0; mg < 2; ++mg)
#pragma unroll
        for (int fn = 0; fn < 11; ++fn)
            acc[mg][fn] = (f32x4){0.f, 0.f, 0.f, 0.f};

    for (int kk = 0; kk < KP; kk += BK) {
        int c0 = tid;
#pragma unroll
        for (int it = 0; it < 4; ++it) {
            int c = it * 256 + c0;
            int row = c >> 3, slot = c & 7;
            int sslot = slot ^ (row & 7);
            const bf16* src = A + (size_t)(m0 + row) * KP + kk + sslot * 8;
            GLOAD(src, ((char*)As) + (size_t)(it * 256 + wave * 64) * 16);
        }
#pragma unroll
        for (int it = 0; it < 6; ++it) {
            int c = it * 256 + c0;
            int row = c >> 3, slot = c & 7;
            int sslot = slot ^ (row & 7);
            const bf16* src = BT + (size_t)(n0 + row) * KP + kk + sslot * 8;
            GLOAD(src, ((char*)Bs) + (size_t)(it * 256 + wave * 64) * 16);
        }
        __syncthreads();
#pragma unroll
        for (int half = 0; half < 2; ++half) {
            int kc = kg + half * 4;
            short8 a[2], b[11];
#pragma unroll
            for (int mg = 0; mg < 2; ++mg) {
                int r = wave * 32 + mg * 16 + ml;
                a[mg] = *(const short8*)(((const char*)As) + (size_t)r * 128 + ((size_t)(kc ^ (r & 7)) << 4));
            }
#pragma unroll
            for (int fn = 0; fn < 11; ++fn) {
                int r = fn * 16 + ml;
                b[fn] = *(const short8*)(((const char*)Bs) + (size_t)r * 128 + ((size_t)(kc ^ (r & 7)) << 4));
            }
#pragma unroll
            for (int mg = 0; mg < 2; ++mg)
#pragma unroll
                for (int fn = 0; fn < 11; ++fn)
                    acc[mg][fn] = __builtin_amdgcn_mfma_f32_16x16x32_bf16(a[mg], b[fn], acc[mg][fn], 0, 0, 0);
        }
        __syncthreads();
    }
#pragma unroll
    for (int mg = 0; mg < 2; ++mg)
#pragma unroll
        for (int fn = 0; fn < 11; ++fn) {
            int col = n0 + fn * 16 + ml;
            if (col < NKV) {
                float bb = bias[col];
#pragma unroll
                for (int r4 = 0; r4 < 4; ++r4) {
                    int row = m0 + wave * 32 + mg * 16 + kg * 4 + r4;
                    kvout[(size_t)row * NKV + col] = __float2bfloat16(acc[mg][fn][r4] + bb);
                }
            }
        }
}

// ---------------- generic 176-col MFMA GEMM, MROWS-templated ------------
// MROWS = 128 or 64 (64 doubles block count for small-M dispatch spread).
// OMODE: 0 = bf16 dense (stride ostride, zero pad cols 176..ostride),
//        1 = fp32 dense (cols < 172), 2 = fp32 scatter rows via g2l[idx[row]]
template<int KP_, int MROWS, bool RELU, int OMODE>
__global__ __launch_bounds__(256) void gemm176_kernel(
    const bf16* __restrict__ A, const bf16* __restrict__ BT,
    const float* __restrict__ bias, void* __restrict__ outp, int ostride,
    const int* __restrict__ idx, const int* __restrict__ g2l) {
    constexpr int WR = MROWS / 4;      // rows per wave (32 or 16)
    constexpr int MG = WR / 16;        // row-groups per wave (2 or 1)
    constexpr int AIT = MROWS / 32;    // A-stage iterations (4 or 2)
    int m0 = blockIdx.x * MROWS;
    __shared__ bf16 As[MROWS][BK];
    __shared__ bf16 Bs[192][BK];
    int tid = threadIdx.x;
    int lane = tid & 63;
    int wave = tid >> 6;
    int ml = lane & 15;
    int kg = lane >> 4;

    f32x4 acc[MG][11];
#pragma unroll
    for (int mg = 0; mg < MG; ++mg)
#pragma unroll
        for (int fn = 0; fn < 11; ++fn)
            acc[mg][fn] = (f32x4){0.f, 0.f, 0.f, 0.f};

    for (int kk = 0; kk < KP_; kk += BK) {
        int c0 = tid;
#pragma unroll
        for (int it = 0; it < AIT; ++it) {
            int c = it * 256 + c0;
            int row = c >> 3, slot = c & 7;
            int sslot = slot ^ (row & 7);
            const bf16* src = A + (size_t)(m0 + row) * KP_ + kk + sslot * 8;
            GLOAD(src, ((char*)As) + (size_t)(it * 256 + wave * 64) * 16);
        }
#pragma unroll
        for (int it = 0; it < 6; ++it) {
            int c = it * 256 + c0;
            int row = c >> 3, slot = c & 7;
            int sslot = slot ^ (row & 7);
            const bf16* src = BT + (size_t)row * KP_ + kk + sslot * 8;
            GLOAD(src, ((char*)Bs) + (size_t)(it * 256 + wave * 64) * 16);
        }
        __syncthreads();
#pragma unroll
        for (int half = 0; half < 2; ++half) {
            int kc = kg + half * 4;
            short8 a[MG], b[11];
#pragma unroll
            for (int mg = 0; mg < MG; ++mg) {
                int r = wave * WR + mg * 16 + ml;
                a[mg] = *(const short8*)(((const char*)As) + (size_t)r * 128 + ((size_t)(kc ^ (r & 7)) << 4));
            }
#pragma unroll
            for (int fn = 0; fn < 11; ++fn) {
                int r = fn * 16 + ml;
                b[fn] = *(const short8*)(((const char*)Bs) + (size_t)r * 128 + ((size_t)(kc ^ (r & 7)) << 4));
            }
#pragma unroll
            for (int mg = 0; mg < MG; ++mg)
#pragma unroll
                for (int fn = 0; fn < 11; ++fn)
                    acc[mg][fn] = __builtin_amdgcn_mfma_f32_16x16x32_bf16(a[mg], b[fn], acc[mg][fn], 0, 0, 0);
        }
        __syncthreads();
    }
#pragma unroll
    for (int mg = 0; mg < MG; ++mg)
#pragma unroll
        for (int fn = 0; fn < 11; ++fn) {
            int col = fn * 16 + ml;
            float bb = bias[col];
#pragma unroll
            for (int r4 = 0; r4 < 4; ++r4) {
                int row = m0 + wave * WR + mg * 16 + kg * 4 + r4;
                float v = acc[mg][fn][r4] + bb;
                if (RELU) v = fmaxf(v, 0.f);
                if (OMODE == 0) {
                    ((bf16*)outp)[(size_t)row * ostride + col] = __float2bfloat16(v);
                } else if (OMODE == 1) {
                    if (col < DD) ((float*)outp)[(size_t)row * ostride + col] = v;
                } else {
                    if (col < DD) {
                        int zr = g2l[idx[row]];
                        ((float*)outp)[(size_t)zr * DD + col] = v;
                    }
                }
            }
        }
    if (OMODE == 0 && ostride > 176) {
        int row = tid >> 1, half = tid & 1;
        if (row < MROWS) {
            short8 zz = (short8){0, 0, 0, 0, 0, 0, 0, 0};
            *(short8*)&((bf16*)outp)[(size_t)(m0 + row) * ostride + 176 + half * 8] = zz;
        }
    }
}

// ---------------- attention over K=20 neighbors (kv packed [row][344]) --
#define ASTR 360
__global__ __launch_bounds__(64) void attn_kernel(
    const float* __restrict__ q, const bf16* __restrict__ kv,
    const void* __restrict__ mask, const int* __restrict__ mode_p,
    const float* __restrict__ sf, const int* __restrict__ idx,
    bf16* __restrict__ f1out) {
    int node = blockIdx.x;
    int lane = threadIdx.x;
    __shared__ unsigned short kvls[KK][ASTR];
    __shared__ float qs[DD];
    __shared__ float sc[HH][KK];
    __shared__ float aw[HH][KK];
    int mode = *mode_p;
    const unsigned short* kvg = (const unsigned short*)(kv + (size_t)node * KK * NKV);
    for (int c = lane; c < 860; c += 64) {          // 20*344/8 = 860 chunks
        int r = c / 43, cc = c % 43;
        *(short8*)&kvls[r][cc * 8] = *(const short8*)(kvg + (size_t)c * 8);
    }
    for (int i = lane; i < DD; i += 64) qs[i] = q[(size_t)node * DD + i];
    __syncthreads();
    if (lane < HH * KK) {
        int h = lane / KK, kx = lane % KK;
        bool mk = get_mask(mask, mode, node * KK + kx);
        float s = 0.f;
        const unsigned short* kr = &kvls[kx][h * DHH];
        for (int d = 0; d < DHH; d++) s += qs[h * DHH + d] * bfu2f(kr[d]);
        sc[h][kx] = mk ? s * 0.10783277320f : -3.0e38f;
    }
    __syncthreads();
    if (lane < HH) {
        int h = lane;
        float m = -3.0e38f;
        for (int k2 = 0; k2 < KK; k2++) m = fmaxf(m, sc[h][k2]);
        float den = 0.f;
        for (int k2 = 0; k2 < KK; k2++) {
            float e = (sc[h][k2] <= -1e37f) ? 0.f : expf(sc[h][k2] - m);
            sc[h][k2] = e;
            den += e;
        }
        float inv = (den > 0.f) ? 1.f / den : 0.f;
        for (int k2 = 0; k2 < KK; k2++) aw[h][k2] = sc[h][k2] * inv;
    }
    __syncthreads();
    bf16* orow = f1out + (size_t)node * F1S;
    for (int jj = lane; jj < DD; jj += 64) {
        int h = jj / DHH;
        float s = 0.f;
        for (int k2 = 0; k2 < KK; k2++)
            s += aw[h][k2] * bfu2f(kvls[k2][DD + jj]);
        orow[jj] = __float2bfloat16(s);
    }
    const float* src = sf + (size_t)idx[node] * DD;
    for (int c = lane; c < F1S - DD; c += 64) {     // cols 172..383: nf then 0
        float v = (c < DD) ? src[c] : 0.f;
        orow[DD + c] = __float2bfloat16(v);
    }
}

// ---------------- launch ------------------------------------------------
extern "C" void kernel_launch(void* const* d_in, const int* in_sizes, int n_in,
                              void* d_out, int out_size, void* d_ws, size_t ws_size,
                              hipStream_t stream) {
    const float* sf     = (const float*)d_in[0];
    const float* time_w = (const float*)d_in[1];
    const float* time_b = (const float*)d_in[2];
    const float* wq  = (const float*)d_in[3];
    const float* bq  = (const float*)d_in[4];
    const float* wk  = (const float*)d_in[5];
    const float* bk  = (const float*)d_in[6];
    const float* wv  = (const float*)d_in[7];
    const float* bv  = (const float*)d_in[8];
    const float* f1w = (const float*)d_in[9];
    const float* f1b = (const float*)d_in[10];
    const float* f2w = (const float*)d_in[11];
    const float* f2b = (const float*)d_in[12];
    const float* times0 = (const float*)d_in[13];
    const float* nbrt0  = (const float*)d_in[14];
    const float* times1 = (const float*)d_in[15];
    const float* nbrt1  = (const float*)d_in[16];
    const float* edge0  = (const float*)d_in[17];
    const float* edge1  = (const float*)d_in[18];
    const int* nids0 = (const int*)d_in[19];
    const int* nbr0  = (const int*)d_in[20];
    const int* nbr1  = (const int*)d_in[21];
    const int* g2l   = (const int*)d_in[22];
    const void* mask0 = d_in[23];
    const void* mask1 = d_in[24];
    float* z = (float*)d_out;

    char* wsp = (char*)d_ws;
    size_t off = 0;
    auto alloc = [&](size_t bytes) -> void* {
        void* p = wsp + off;
        off += (bytes + 255) & ~(size_t)255;
        return p;
    };
    int*   mode   = (int*)alloc(4);
    bf16*  wkvT   = (bf16*)alloc((size_t)2 * NPADR * KP * sizeof(bf16));
    float* biaskv = (float*)alloc(2 * 352 * sizeof(float));
    bf16*  wqT    = (bf16*)alloc((size_t)2 * 192 * QS * sizeof(bf16));
    float* biasq  = (float*)alloc(2 * 176 * sizeof(float));
    bf16*  f1T    = (bf16*)alloc((size_t)2 * 192 * F1S * sizeof(bf16));
    float* biasf1 = (float*)alloc(2 * 176 * sizeof(float));
    bf16*  f2T    = (bf16*)alloc((size_t)2 * 192 * HS * sizeof(bf16));
    float* biasf2 = (float*)alloc(2 * 176 * sizeof(float));
    bf16*  qin1 = (bf16*)alloc((size_t)N1C * QS * sizeof(bf16));
    bf16*  qin0 = (bf16*)alloc((size_t)N0C * QS * sizeof(bf16));
    float* q1 = (float*)alloc((size_t)N1C * DD * sizeof(float));
    float* q0 = (float*)alloc((size_t)N0C * DD * sizeof(float));
    bf16*  f1in1 = (bf16*)alloc((size_t)N1C * F1S * sizeof(bf16));
    bf16*  f1in0 = (bf16*)alloc((size_t)N0C * F1S * sizeof(bf16));
    bf16*  h1 = (bf16*)alloc((size_t)N1C * HS * sizeof(bf16));
    bf16*  h0 = (bf16*)alloc((size_t)N0C * HS * sizeof(bf16));
    bf16*  kv1 = (bf16*)alloc((size_t)M1 * NKV * sizeof(bf16));
    bf16*  kv0 = (bf16*)alloc((size_t)M0 * NKV * sizeof(bf16));
    size_t avail = (ws_size > off) ? (ws_size - off) : 0;
    size_t rows_fit = avail / ((size_t)KP * sizeof(bf16));
    long chunkRows = (long)((rows_fit / BM) * BM);
    if (chunkRows > M1) chunkRows = M1;
    if (chunkRows < BM) chunkRows = BM;
    bf16* Achunk = (bf16*)(wsp + off);

    // one mega-prep launch (wkvT + wq/f1/f2 transposes + mask probe)
    prep_mega_kernel<<<2689, 256, 0, stream>>>(
        wk, wv, bk, bv, wq, bq, f1w, f1b, f2w, f2b,
        wkvT, biaskv, wqT, biasq, f1T, biasf1, f2T, biasf2,
        (const unsigned*)mask1, (N1C * KK) / 4, mode);

    // independent q paths first (fills pipeline, off layer-0 critical chain)
    stage_qin_kernel<<<N1C / 4, 256, 0, stream>>>(sf, nbr0, time_b, qin1);
    stage_qin_kernel<<<N0C / 4, 256, 0, stream>>>(sf, nids0, time_b, qin0);
    gemm176_kernel<QS, 64, false, 1><<<N1C / 64, 256, 0, stream>>>(
        qin1, wqT + (size_t)192 * QS, biasq + 176, q1, DD, nullptr, nullptr);
    gemm176_kernel<QS, 64, false, 1><<<N0C / 64, 256, 0, stream>>>(
        qin0, wqT, biasq, q0, DD, nullptr, nullptr);

    // ---- layer 1 ----
    for (long r0 = 0; r0 < M1; r0 += chunkRows) {
        long rows = M1 - r0 < chunkRows ? M1 - r0 : chunkRows;
        stage_kvin_kernel<<<(int)(rows / 4), 256, 0, stream>>>(
            sf, nbr1, edge1, times1, nbrt1, mask1, mode, time_w, time_b,
            nullptr, g2l, 0, (int)r0, Achunk);
        gemm_kv_kernel<<<(int)((rows / BM) * 2), 256, 0, stream>>>(
            Achunk, wkvT + (size_t)NPADR * KP, biaskv + 352,
            kv1 + (size_t)r0 * NKV, (int)(rows / BM));
    }
    attn_kernel<<<N1C, 64, 0, stream>>>(q1, kv1, mask1, mode, sf, nbr0, f1in1);
    gemm176_kernel<F1S, 64, true, 0><<<N1C / 64, 256, 0, stream>>>(
        f1in1, f1T + (size_t)192 * F1S, biasf1 + 176, h1, HS, nullptr, nullptr);
    gemm176_kernel<HS, 64, false, 2><<<N1C / 64, 256, 0, stream>>>(
        h1, f2T + (size_t)192 * HS, biasf2 + 176, z, DD, nbr0, g2l);

    // ---- layer 0 (q0 already done) ----
    for (long r0 = 0; r0 < M0; r0 += chunkRows) {
        long rows = M0 - r0 < chunkRows ? M0 - r0 : chunkRows;
        stage_kvin_kernel<<<(int)(rows / 4), 256, 0, stream>>>(
            sf, nbr0, edge0, times0, nbrt0, mask0, mode, time_w, time_b,
            z, g2l, 1, (int)r0, Achunk);
        gemm_kv_kernel<<<(int)((rows / BM) * 2), 256, 0, stream>>>(
            Achunk, wkvT, biaskv,
            kv0 + (size_t)r0 * NKV, (int)(rows / BM));
    }
    attn_kernel<<<N0C, 64, 0, stream>>>(q0, kv0, mask0, mode, sf, nids0, f1in0);
    gemm176_kernel<F1S, 64, true, 0><<<N0C / 64, 256, 0, stream>>>(
        f1in0, f1T, biasf1, h0, HS, nullptr, nullptr);
    gemm176_kernel<HS, 64, false, 2><<<N0C / 64, 256, 0, stream>>>(
        h0, f2T, biasf2, z, DD, nids0, g2l);
}